// Round 8
// baseline (204.704 us; speedup 1.0000x reference)
//
#include <hip/hip_runtime.h>
#include <math.h>

#define BN    16
#define NGTC  32
#define NB    2048      // 11-bit value buckets: float_bits >> 21
#define BSH   21
#define BLK   256
#define ANC   8         // anchors per thread: 1 ds_read + 1 ds_atomic per 8 pairs
#define CNTSH 40        // count field shift in packed u64 histogram
#define FPS   1048576.0f // 2^20 fixed-point scale for packed sum

struct Accum {
  unsigned int npos[BN];
  float pos_sum;
  float box_sum;
  unsigned int counter;   // last-block ticket
};

__device__ inline float wred_sum_f(float v) {
#pragma unroll
  for (int o = 32; o > 0; o >>= 1) v += __shfl_down(v, o, 64);
  return v;
}
__device__ inline unsigned wred_sum_u(unsigned v) {
#pragma unroll
  for (int o = 32; o > 0; o >>= 1) v += __shfl_down(v, o, 64);
  return v;
}
__device__ inline float sl1(float d) {
  float ad = fabsf(d);
  return ad < 1.f ? 0.5f * d * d : ad - 0.5f;
}
// Same code in main pass and correction pass so swaps cancel bit-exactly.
__device__ inline float boxterm(float4 av, float4 g, float4 p) {
  float acx = (av.x + av.z) * 0.5f, acy = (av.y + av.w) * 0.5f;
  float aw = av.z - av.x, ah = av.w - av.y;
  float gcx = (g.x + g.z) * 0.5f, gcy = (g.y + g.w) * 0.5f;
  float gw = g.z - g.x, gh = g.w - g.y;
  float t0 = (gcx - acx) / (aw / 10.f);
  float t1 = (gcy - acy) / (ah / 10.f);
  float t2 = __logf(gw / aw) * 5.f;
  float t3 = __logf(gh / ah) * 5.f;
  return sl1(p.x - t0) + sl1(p.y - t1) + sl1(p.z - t2) + sl1(p.w - t3);
}
// Agent-scope loads: bypass L1 (graph replays reuse ws; per-CU L1 is not
// coherent with other CUs' writes/atomics, and the "last block" CU varies).
__device__ inline unsigned aload_u(const unsigned* p) {
  return __hip_atomic_load(p, __ATOMIC_RELAXED, __HIP_MEMORY_SCOPE_AGENT);
}
__device__ inline float aload_f(const float* p) {
  return __hip_atomic_load(p, __ATOMIC_RELAXED, __HIP_MEMORY_SCOPE_AGENT);
}
__device__ inline unsigned long long aload_u64(const unsigned long long* p) {
  return __hip_atomic_load(p, __ATOMIC_RELAXED, __HIP_MEMORY_SCOPE_AGENT);
}

// Single fused kernel. Per block: per-anchor argmax (division-free) + losses +
// packed LDS histogram + per-(b,gt) partial argmax keys. The LAST block to
// finish (ticket counter) runs the epilogue: forced-match corrections (kept in
// LDS) + per-row suffix-select + final combine.
// Measured lessons: (R4) no min-waves in launch_bounds (spills). (R5) no
// read-guard on ds atomics; cap unroll. (R7) one ds_read + one ds_atomic per
// 8 anchor-pairs — DS pipe and in-order lgkmcnt were the stall, not occupancy.
__global__ __launch_bounds__(BLK) void k_main(
    const float* __restrict__ labels, const float4* __restrict__ poffs,
    const float4* __restrict__ anchors, const float4* __restrict__ gt,
    Accum* __restrict__ acc, unsigned long long* __restrict__ partial,
    unsigned int* __restrict__ ghc, float* __restrict__ ghs,
    float* __restrict__ out, int A, int nbx) {
  __shared__ unsigned long long hist[NB];   // (count<<40) | fixedpoint-sum
  __shared__ unsigned long long sbest[NGTC];
  __shared__ float4 sgt[NGTC];
  __shared__ float sredf[BLK / 64], sredb[BLK / 64];
  __shared__ unsigned sredu[BLK / 64];
  __shared__ unsigned slast;
  // epilogue-only LDS (last block)
  __shared__ unsigned sa2[BN * NGTC];
  __shared__ unsigned scc[BLK];
  __shared__ float    scs[BLK];
  __shared__ unsigned cbk[BN][NGTC];
  __shared__ float    csp[BN][NGTC];
  __shared__ unsigned ncorr[BN], dnp[BN];
  __shared__ float    shard[BN];
  __shared__ float    dbox, dpos;

  int b = blockIdx.y, t = threadIdx.x;
  for (int i = t; i < NB; i += BLK) hist[i] = 0ull;
  if (t < NGTC) { sgt[t] = gt[b * NGTC + t]; sbest[t] = 0ull; }
  __syncthreads();

  int base = blockIdx.x * (ANC * BLK) + t;
  float4 av[ANC];
  float ar[ANC], bn[ANC], bd[ANC];
  int gid[ANC];
#pragma unroll
  for (int q = 0; q < ANC; ++q) {
    int a = base + q * BLK;
    // invalid anchors -> degenerate far box: inter==0 with every gt
    av[q] = (a < A) ? anchors[a] : make_float4(2.f, 2.f, 2.f, 2.f);
    ar[q] = (av[q].z - av[q].x) * (av[q].w - av[q].y);
    bn[q] = -1.f; bd[q] = 1.f; gid[q] = 0;
  }

  int rot = t & 31;
#pragma unroll 2
  for (int jj = 0; jj < NGTC; ++jj) {
    int j = (jj + rot) & 31;    // stagger lanes across the 32 sbest slots
    float4 g = sgt[j];
    float ga = (g.z - g.x) * (g.w - g.y);
    unsigned long long lkey = 0ull;
#pragma unroll
    for (int q = 0; q < ANC; ++q) {
      float w = fmaxf(fminf(av[q].z, g.z) - fmaxf(av[q].x, g.x), 0.f);
      float h = fmaxf(fminf(av[q].w, g.w) - fmaxf(av[q].y, g.y), 0.f);
      float inter = w * h;
      float d = ar[q] + ga - inter;
      if (inter * bd[q] > bn[q] * d) { bn[q] = inter; bd[q] = d; gid[q] = j; }
      if (inter > 0.f) {
        float iou = inter * __builtin_amdgcn_rcpf(d);  // ordering key only
        unsigned long long key =
            (((unsigned long long)__float_as_uint(iou)) << 32) |
            (unsigned)(~(unsigned)(base + q * BLK));
        lkey = key > lkey ? key : lkey;   // (max iou, then smallest a)
      }
    }
    if (lkey) atomicMax(&sbest[j], lkey);  // one ds_atomic per 8 pairs
  }

  float psum = 0.f, bsum = 0.f;
  unsigned cnt = 0u;
  size_t bA = (size_t)b * A;
#pragma unroll
  for (int q = 0; q < ANC; ++q) {
    int a = base + q * BLK;
    if (a < A) {
      bool pos = bn[q] > 0.3f * bd[q];
      float x = labels[bA + a];
      float e = __expf(-fabsf(x));
      float sp = fmaxf(x, 0.f) + __logf(1.f + e);   // softplus = bce(y=0)
      if (pos) {
        cnt++; psum += sp - x;                       // bce(y=1)
        float4 p = poffs[bA + a];
        bsum += boxterm(av[q], sgt[gid[q]], p);
      } else {
        unsigned bk = __float_as_uint(sp) >> BSH;
        atomicAdd(&hist[bk],
                  (1ull << CNTSH) + (unsigned long long)(unsigned)(sp * FPS + 0.5f));
      }
    }
  }
  __syncthreads();
  if (t < NGTC)
    partial[(size_t)blockIdx.x * (BN * NGTC) + b * NGTC + t] = sbest[t];

  psum = wred_sum_f(psum);
  bsum = wred_sum_f(bsum);
  cnt  = wred_sum_u(cnt);
  int wid = t >> 6, lane = t & 63;
  if (lane == 0) { sredf[wid] = psum; sredb[wid] = bsum; sredu[wid] = cnt; }
  __syncthreads();
  if (t == 0) {
    float ps = 0.f, bs = 0.f; unsigned c = 0;
#pragma unroll
    for (int w2 = 0; w2 < BLK / 64; ++w2) { ps += sredf[w2]; bs += sredb[w2]; c += sredu[w2]; }
    if (c) atomicAdd(&acc->npos[b], c);
    atomicAdd(&acc->pos_sum, ps);
    atomicAdd(&acc->box_sum, bs);
  }
  for (int i = t; i < NB; i += BLK) {
    unsigned long long pk = hist[i];
    if (pk) {
      atomicAdd(&ghc[(size_t)b * NB + i], (unsigned)(pk >> CNTSH));
      atomicAdd(&ghs[(size_t)b * NB + i],
                (float)(pk & ((1ull << CNTSH) - 1ull)) * (1.f / FPS));
    }
  }

  // ---- last-block ticket ----
  __threadfence();            // each thread drains its stores/atomics
  __syncthreads();
  if (t == 0) slast = atomicAdd(&acc->counter, 1u);
  __syncthreads();
  if (slast != (unsigned)(gridDim.x * gridDim.y) - 1u) return;
  __threadfence();            // acquire: see all blocks' writes

  // ================= epilogue (one block, 256 threads) =================
  if (t < BN) { ncorr[t] = 0u; dnp[t] = 0u; }
  if (t == 0) { dbox = 0.f; dpos = 0.f; }
  __syncthreads();

  // A1: reduce partial keys -> best anchor per (b,gt)
  for (int p = t; p < BN * NGTC; p += BLK) {
    unsigned long long best = 0ull;
    for (int i = 0; i < nbx; ++i) {
      unsigned long long v = aload_u64(&partial[(size_t)i * (BN * NGTC) + p]);
      best = v > best ? v : best;
    }
    if (best == 0ull) best = 0xFFFFFFFFull;  // no overlap -> anchor 0
    sa2[p] = ~(unsigned)(best & 0xFFFFFFFFull);
  }
  __syncthreads();

  // A2: duplicate resolution (last j wins) + corrections into LDS
  for (int p = t; p < BN * NGTC; p += BLK) {
    int pb = p >> 5, j = p & 31;
    unsigned a = sa2[p];
    bool winner = true;
    for (int j2 = j + 1; j2 < NGTC; ++j2)
      if (sa2[(pb << 5) | j2] == a) { winner = false; break; }
    if (!winner) continue;
    // Replicate main pass for anchor a EXACTLY (same rot, same op order).
    float4 avx = anchors[a];
    float area_a = (avx.z - avx.x) * (avx.w - avx.y);
    int rot2 = (int)(a & 31u);   // a % BLK masked to 31 == a & 31
    float bn2 = -1.f, bd2 = 1.f;
    int gid2 = 0;
    for (int jj = 0; jj < NGTC; ++jj) {
      int j2 = (jj + rot2) & 31;
      float4 g = gt[pb * NGTC + j2];
      float w = fmaxf(fminf(avx.z, g.z) - fmaxf(avx.x, g.x), 0.f);
      float h = fmaxf(fminf(avx.w, g.w) - fmaxf(avx.y, g.y), 0.f);
      float inter = w * h;
      float dj = area_a + (g.z - g.x) * (g.w - g.y) - inter;
      if (inter * bd2 > bn2 * dj) { bn2 = inter; bd2 = dj; gid2 = j2; }
    }
    bool tpos = bn2 > 0.3f * bd2;
    float4 p4 = poffs[(size_t)pb * A + a];
    float newbox = boxterm(avx, gt[pb * NGTC + j], p4);
    if (tpos) {
      if (gid2 != j) {   // box target overridden: swap terms
        float oldbox = boxterm(avx, gt[pb * NGTC + gid2], p4);
        atomicAdd(&dbox, newbox - oldbox);
      }
    } else {             // was counted negative: promote to positive
      float x = labels[(size_t)pb * A + a];
      float e = __expf(-fabsf(x));
      float sp = fmaxf(x, 0.f) + __logf(1.f + e);
      atomicAdd(&dnp[pb], 1u);
      atomicAdd(&dpos, sp - x);
      atomicAdd(&dbox, newbox);
      unsigned idx = atomicAdd(&ncorr[pb], 1u);   // <= 32 per row
      cbk[pb][idx] = __float_as_uint(sp) >> BSH;
      csp[pb][idx] = sp;
    }
  }
  __syncthreads();

  // B: per-row suffix-select top-(3*n_pos); wave wv handles rows wv,wv+4,...
  int wv = t >> 6, ln = t & 63;
  const int CH = NB / 64;   // 32 buckets per lane chunk
  for (int bb = wv; bb < BN; bb += BLK / 64) {
    unsigned cm = 0; float sm = 0.f;
    int c0 = ln * CH;
    size_t hb = (size_t)bb * NB + c0;
    for (int i = 0; i < CH; ++i) { cm += aload_u(&ghc[hb + i]); sm += aload_f(&ghs[hb + i]); }
    unsigned nc = ncorr[bb];
    for (unsigned c = 0; c < nc; ++c) {
      unsigned bk = cbk[bb][c];
      if ((int)bk >= c0 && (int)bk < c0 + CH) { cm -= 1u; sm -= csp[bb][c]; }
    }
    scc[wv * 64 + ln] = cm; scs[wv * 64 + ln] = sm;
    __syncthreads();
    if (ln == 0) {
      unsigned k = 3u * (aload_u(&acc->npos[bb]) + dnp[bb]);
      unsigned cum = 0; float hard = 0.f; int cb = -1;
      for (int q2 = 63; q2 >= 0; --q2) {
        unsigned c2 = scc[wv * 64 + q2];
        if (cum + c2 >= k) { cb = q2; break; }
        cum += c2; hard += scs[wv * 64 + q2];
      }
      if (cb >= 0) {
        for (int u = CH - 1; u >= 0; --u) {
          int bk = cb * CH + u;
          unsigned c2 = aload_u(&ghc[(size_t)bb * NB + bk]);
          float s2 = aload_f(&ghs[(size_t)bb * NB + bk]);
          for (unsigned c = 0; c < nc; ++c)
            if (cbk[bb][c] == (unsigned)bk) { c2 -= 1u; s2 -= csp[bb][c]; }
          if (cum + c2 >= k) {
            unsigned r = k - cum;
            if (c2 && r) {
              float m  = s2 / (float)c2;
              float lo = __uint_as_float((unsigned)bk << BSH);
              float hi = __uint_as_float((unsigned)(bk + 1) << BSH);
              // uniform-within-bucket model; exact at r==c2
              hard += (float)r * m +
                      (float)r * (float)(c2 - r) * (hi - lo) / (2.f * (float)c2);
            }
            break;
          }
          cum += c2; hard += s2;
        }
      }
      shard[bb] = hard;
    }
    __syncthreads();
  }

  // C: combine
  if (t == 0) {
    unsigned npt = 0; float hard = 0.f;
    for (int bb = 0; bb < BN; ++bb) {
      npt += aload_u(&acc->npos[bb]) + dnp[bb];
      hard += shard[bb];
    }
    float npf = (float)npt;
    float box = (aload_f(&acc->box_sum) + dbox) / (npf * 4.f);
    float cls = (hard + aload_f(&acc->pos_sum) + dpos) / npf;
    out[0] = box + cls;
    out[1] = box;
    out[2] = cls;
  }
}

extern "C" void kernel_launch(void* const* d_in, const int* in_sizes, int n_in,
                              void* d_out, int out_size, void* d_ws, size_t ws_size,
                              hipStream_t stream) {
  const float*  labels  = (const float*)d_in[0];
  const float4* poffs   = (const float4*)d_in[1];
  const float4* anchors = (const float4*)d_in[2];
  const float4* gt      = (const float4*)d_in[3];
  int A = in_sizes[2] / 4;  // 100000

  char* ws = (char*)d_ws;
  Accum* acc = (Accum*)ws;
  size_t off_hc = (sizeof(Accum) + 255) & ~(size_t)255;
  unsigned int* ghc = (unsigned int*)(ws + off_hc);
  size_t off_hs = off_hc + (size_t)BN * NB * sizeof(unsigned int);
  float* ghs = (float*)(ws + off_hs);
  size_t off_part = off_hs + (size_t)BN * NB * sizeof(float);
  unsigned long long* partial = (unsigned long long*)(ws + off_part);
  // partial (nbx*512 u64) fully written by k_main each call; no memset needed.

  hipMemsetAsync(ws, 0, off_part, stream);  // Accum(+counter) + histograms

  int nbx = (A + ANC * BLK - 1) / (ANC * BLK);   // 49
  dim3 grid(nbx, BN);
  k_main<<<grid, BLK, 0, stream>>>(labels, poffs, anchors, gt, acc, partial,
                                   ghc, ghs, (float*)d_out, A, nbx);
}

// Round 9
// 129.790 us; speedup vs baseline: 1.5772x; 1.5772x over previous
//
#include <hip/hip_runtime.h>
#include <math.h>

#define BN    16
#define NGTC  32
#define NB    2048      // 11-bit value buckets: float_bits >> 21
#define BSH   21
#define BLK   256
#define GX    64        // k_main blocks per batch row
#define CNTSH 40        // count field shift in packed u64 histogram
#define FPS   1048576.0f // 2^20 fixed-point scale for packed sum

struct Accum {
  unsigned int npos[BN];
  float pos_sum;
  float box_sum;
  unsigned int counter;     // k_post 16-block ticket
  unsigned int rw_np[BN];   // per-row corrected n_pos (k_post)
  float rw_hard[BN];        // per-row hard-negative sum (k_post)
};

__device__ inline float wred_sum_f(float v) {
#pragma unroll
  for (int o = 32; o > 0; o >>= 1) v += __shfl_down(v, o, 64);
  return v;
}
__device__ inline unsigned wred_sum_u(unsigned v) {
#pragma unroll
  for (int o = 32; o > 0; o >>= 1) v += __shfl_down(v, o, 64);
  return v;
}
__device__ inline float sl1(float d) {
  float ad = fabsf(d);
  return ad < 1.f ? 0.5f * d * d : ad - 0.5f;
}
// Same code in k_main and k_post so correction swaps cancel bit-exactly.
__device__ inline float boxterm(float4 av, float4 g, float4 p) {
  float acx = (av.x + av.z) * 0.5f, acy = (av.y + av.w) * 0.5f;
  float aw = av.z - av.x, ah = av.w - av.y;
  float gcx = (g.x + g.z) * 0.5f, gcy = (g.y + g.w) * 0.5f;
  float gw = g.z - g.x, gh = g.w - g.y;
  float t0 = (gcx - acx) / (aw / 10.f);
  float t1 = (gcy - acy) / (ah / 10.f);
  float t2 = __logf(gw / aw) * 5.f;
  float t3 = __logf(gh / ah) * 5.f;
  return sl1(p.x - t0) + sl1(p.y - t1) + sl1(p.z - t2) + sl1(p.w - t3);
}
// Agent-scope loads (k_post final combine only: cross-block, same kernel).
__device__ inline unsigned aload_u(const unsigned* p) {
  return __hip_atomic_load(p, __ATOMIC_RELAXED, __HIP_MEMORY_SCOPE_AGENT);
}
__device__ inline float aload_f(const float* p) {
  return __hip_atomic_load(p, __ATOMIC_RELAXED, __HIP_MEMORY_SCOPE_AGENT);
}

// Fused main pass (R6 structure + measured fixes):
//  (R4) no min-waves in launch_bounds (VGPR cap -> scratch spills).
//  (R5) no read-guard on ds atomics; cap unroll (full unroll -> 176 VGPR).
//  (R7) DS pipe + in-order lgkmcnt is the stall: no sarea ds_read (VALU
//       recompute), and the 2 anchors' keys fold to ONE ds_atomic per jj.
//  (R8) epilogue must not be a serial one-block tail -> separate k_post.
__global__ __launch_bounds__(BLK) void k_main(
    const float* __restrict__ labels, const float4* __restrict__ poffs,
    const float4* __restrict__ anchors, const float4* __restrict__ gt,
    Accum* __restrict__ acc, unsigned long long* __restrict__ partial,
    unsigned int* __restrict__ ghc, float* __restrict__ ghs, int A) {
  __shared__ unsigned long long hist[NB];   // (count<<40) | fixedpoint-sum
  __shared__ unsigned long long sbest[NGTC];
  __shared__ float4 sgt[NGTC];
  __shared__ float sredf[BLK / 64], sredb[BLK / 64];
  __shared__ unsigned sredu[BLK / 64];
  int b = blockIdx.y, t = threadIdx.x;
  for (int i = t; i < NB; i += BLK) hist[i] = 0ull;
  if (t < NGTC) { sgt[t] = gt[b * NGTC + t]; sbest[t] = 0ull; }
  __syncthreads();

  float psum = 0.f, bsum = 0.f;
  unsigned cnt = 0u;
  int rot = t & 31;
  for (int a0 = blockIdx.x * (2 * BLK) + t; a0 < A; a0 += GX * 2 * BLK) {
    int a1 = a0 + BLK;
    bool v1 = a1 < A;
    float4 av0 = anchors[a0];
    // invalid -> degenerate far box: inter==0 with every gt
    float4 av1 = v1 ? anchors[a1] : make_float4(2.f, 2.f, 2.f, 2.f);
    float area0 = (av0.z - av0.x) * (av0.w - av0.y);
    float area1 = (av1.z - av1.x) * (av1.w - av1.y);
    float bn0 = -1.f, bd0 = 1.f, bn1 = -1.f, bd1 = 1.f;
    int gid0 = 0, gid1 = 0;
#pragma unroll 8
    for (int jj = 0; jj < NGTC; ++jj) {
      int j = (jj + rot) & 31;    // stagger lanes across the 32 sbest slots
      float4 g = sgt[j];
      float ga = (g.z - g.x) * (g.w - g.y);   // VALU, not LDS (R7)
      float w0 = fmaxf(fminf(av0.z, g.z) - fmaxf(av0.x, g.x), 0.f);
      float h0 = fmaxf(fminf(av0.w, g.w) - fmaxf(av0.y, g.y), 0.f);
      float i0 = w0 * h0;
      float d0 = area0 + ga - i0;
      if (i0 * bd0 > bn0 * d0) { bn0 = i0; bd0 = d0; gid0 = j; }
      float w1 = fmaxf(fminf(av1.z, g.z) - fmaxf(av1.x, g.x), 0.f);
      float h1 = fmaxf(fminf(av1.w, g.w) - fmaxf(av1.y, g.y), 0.f);
      float i1 = w1 * h1;
      float d1 = area1 + ga - i1;
      if (i1 * bd1 > bn1 * d1) { bn1 = i1; bd1 = d1; gid1 = j; }
      unsigned long long lkey = 0ull;
      if (i0 > 0.f) {
        float iou = i0 * __builtin_amdgcn_rcpf(d0);  // ordering key only
        lkey = (((unsigned long long)__float_as_uint(iou)) << 32) |
               (unsigned)(~(unsigned)a0);
      }
      if (i1 > 0.f) {
        float iou = i1 * __builtin_amdgcn_rcpf(d1);
        unsigned long long k2 =
            (((unsigned long long)__float_as_uint(iou)) << 32) |
            (unsigned)(~(unsigned)a1);
        lkey = k2 > lkey ? k2 : lkey;
      }
      if (lkey) atomicMax(&sbest[j], lkey);  // one ds_atomic per jj (R7)
    }
#pragma unroll
    for (int q = 0; q < 2; ++q) {
      int a = q ? a1 : a0;
      if (q && !v1) break;
      float4 av = q ? av1 : av0;
      float bn = q ? bn1 : bn0, bd = q ? bd1 : bd0;
      int gid = q ? gid1 : gid0;
      bool pos = bn > 0.3f * bd;
      float x = labels[(size_t)b * A + a];
      float e = __expf(-fabsf(x));
      float sp = fmaxf(x, 0.f) + __logf(1.f + e);   // softplus = bce(y=0)
      if (pos) {
        cnt++; psum += sp - x;                       // bce(y=1)
        float4 p = poffs[(size_t)b * A + a];
        bsum += boxterm(av, sgt[gid], p);
      } else {
        unsigned bk = __float_as_uint(sp) >> BSH;
        atomicAdd(&hist[bk],
                  (1ull << CNTSH) + (unsigned long long)(unsigned)(sp * FPS + 0.5f));
      }
    }
  }
  __syncthreads();
  if (t < NGTC)
    partial[(size_t)blockIdx.x * (BN * NGTC) + b * NGTC + t] = sbest[t];

  psum = wred_sum_f(psum);
  bsum = wred_sum_f(bsum);
  cnt  = wred_sum_u(cnt);
  int wid = t >> 6, lane = t & 63;
  if (lane == 0) { sredf[wid] = psum; sredb[wid] = bsum; sredu[wid] = cnt; }
  __syncthreads();
  if (t == 0) {
    float ps = 0.f, bs = 0.f; unsigned c = 0;
#pragma unroll
    for (int w2 = 0; w2 < BLK / 64; ++w2) { ps += sredf[w2]; bs += sredb[w2]; c += sredu[w2]; }
    if (c) atomicAdd(&acc->npos[b], c);
    atomicAdd(&acc->pos_sum, ps);
    atomicAdd(&acc->box_sum, bs);
  }
  for (int i = t; i < NB; i += BLK) {
    unsigned long long pk = hist[i];
    if (pk) {
      atomicAdd(&ghc[(size_t)b * NB + i], (unsigned)(pk >> CNTSH));
      atomicAdd(&ghs[(size_t)b * NB + i],
                (float)(pk & ((1ull << CNTSH) - 1ull)) * (1.f / FPS));
    }
  }
}

// Parallel epilogue: one block per batch row. Histogram staged to LDS
// (plain loads: kernel boundary flushed L2), corrections in LDS, suffix-
// select in LDS. 16-block ticket for the trivial final combine.
__global__ __launch_bounds__(BLK) void k_post(
    const float* __restrict__ labels, const float4* __restrict__ poffs,
    const float4* __restrict__ anchors, const float4* __restrict__ gt,
    Accum* __restrict__ acc, const unsigned long long* __restrict__ partial,
    const unsigned int* __restrict__ ghc, const float* __restrict__ ghs,
    float* __restrict__ out, int A, int nbx) {
  __shared__ unsigned hc[NB];
  __shared__ float    hsum[NB];
  __shared__ unsigned scc[BLK];
  __shared__ float    scs[BLK];
  __shared__ unsigned sa[NGTC];
  __shared__ float sdpos, sdbox;
  __shared__ unsigned sdnp;
  int b = blockIdx.x, t = threadIdx.x;

  // stage row histogram into LDS (coalesced) + reduce partial keys
  for (int i = t; i < NB; i += BLK) {
    hc[i] = ghc[(size_t)b * NB + i];
    hsum[i] = ghs[(size_t)b * NB + i];
  }
  if (t < NGTC) {
    unsigned long long best = 0ull;
    for (int i = 0; i < nbx; ++i) {
      unsigned long long v = partial[(size_t)i * (BN * NGTC) + b * NGTC + t];
      best = v > best ? v : best;
    }
    if (best == 0ull) best = 0xFFFFFFFFull;  // no overlap -> anchor 0
    sa[t] = ~(unsigned)(best & 0xFFFFFFFFull);
  }
  if (t == 0) { sdpos = 0.f; sdbox = 0.f; sdnp = 0u; }
  __syncthreads();

  // forced-match corrections (threads 0..31, one per gt)
  if (t < NGTC) {
    unsigned a = sa[t];
    bool winner = true;
    for (int j2 = t + 1; j2 < NGTC; ++j2)
      if (sa[j2] == a) { winner = false; break; }  // last j wins
    if (winner) {
      // Replicate k_main's per-anchor pass EXACTLY (same rot, same op order).
      float4 avx = anchors[a];
      float area_a = (avx.z - avx.x) * (avx.w - avx.y);
      int rot = (int)(a & 31u);   // a == t (mod 256) in k_main
      float bn = -1.f, bd = 1.f;
      int gid = 0;
      for (int jj = 0; jj < NGTC; ++jj) {
        int j2 = (jj + rot) & 31;
        float4 g = gt[b * NGTC + j2];
        float ga = (g.z - g.x) * (g.w - g.y);
        float w = fmaxf(fminf(avx.z, g.z) - fmaxf(avx.x, g.x), 0.f);
        float h = fmaxf(fminf(avx.w, g.w) - fmaxf(avx.y, g.y), 0.f);
        float inter = w * h;
        float dj = area_a + ga - inter;
        if (inter * bd > bn * dj) { bn = inter; bd = dj; gid = j2; }
      }
      bool tpos = bn > 0.3f * bd;
      float4 p4 = poffs[(size_t)b * A + a];
      float newbox = boxterm(avx, gt[b * NGTC + t], p4);
      if (tpos) {
        if (gid != t) {   // box target overridden: swap terms
          float oldbox = boxterm(avx, gt[b * NGTC + gid], p4);
          atomicAdd(&sdbox, newbox - oldbox);
        }
      } else {            // was counted negative: promote to positive
        float x = labels[(size_t)b * A + a];
        float e = __expf(-fabsf(x));
        float sp = fmaxf(x, 0.f) + __logf(1.f + e);
        atomicAdd(&sdnp, 1u);
        atomicAdd(&sdpos, sp - x);
        atomicAdd(&sdbox, newbox);
        unsigned bk = __float_as_uint(sp) >> BSH;
        atomicSub(&hc[bk], 1u);
        atomicAdd(&hsum[bk], -sp);
      }
    }
  }
  __syncthreads();

  // chunk sums (8 buckets/thread), then LDS-resident suffix-select
  {
    unsigned cm = 0; float sm = 0.f;
    int base = t * (NB / BLK);
#pragma unroll
    for (int i = 0; i < NB / BLK; ++i) { cm += hc[base + i]; sm += hsum[base + i]; }
    scc[t] = cm; scs[t] = sm;
  }
  __syncthreads();
  if (t == 0) {
    unsigned np_b = acc->npos[b] + sdnp;
    unsigned k = 3u * np_b;
    unsigned cum = 0; float hard = 0.f; int cb = -1;
    for (int q = BLK - 1; q >= 0; --q) {
      unsigned c = scc[q];
      if (cum + c >= k) { cb = q; break; }
      cum += c; hard += scs[q];
    }
    if (cb >= 0) {
      for (int u = NB / BLK - 1; u >= 0; --u) {
        int bk = cb * (NB / BLK) + u;
        unsigned c2 = hc[bk];
        if (cum + c2 >= k) {
          unsigned r = k - cum;
          if (c2 && r) {
            float m  = hsum[bk] / (float)c2;
            float lo = __uint_as_float((unsigned)bk << BSH);
            float hi = __uint_as_float((unsigned)(bk + 1) << BSH);
            // uniform-within-bucket model; exact at r==c2
            hard += (float)r * m +
                    (float)r * (float)(c2 - r) * (hi - lo) / (2.f * (float)c2);
          }
          break;
        }
        cum += c2; hard += hsum[bk];
      }
    }
    acc->rw_np[b] = np_b;
    acc->rw_hard[b] = hard;
    atomicAdd(&acc->pos_sum, sdpos);
    atomicAdd(&acc->box_sum, sdbox);
    __threadfence();
    unsigned tk = atomicAdd(&acc->counter, 1u);
    if (tk == BN - 1u) {       // last row block: final combine (34 loads)
      __threadfence();
      unsigned npt = 0; float hardt = 0.f;
      for (int bb = 0; bb < BN; ++bb) {
        npt += aload_u(&acc->rw_np[bb]);
        hardt += aload_f(&acc->rw_hard[bb]);
      }
      float npf = (float)npt;
      float box = aload_f(&acc->box_sum) / (npf * 4.f);
      float cls = (hardt + aload_f(&acc->pos_sum)) / npf;
      out[0] = box + cls;
      out[1] = box;
      out[2] = cls;
    }
  }
}

extern "C" void kernel_launch(void* const* d_in, const int* in_sizes, int n_in,
                              void* d_out, int out_size, void* d_ws, size_t ws_size,
                              hipStream_t stream) {
  const float*  labels  = (const float*)d_in[0];
  const float4* poffs   = (const float4*)d_in[1];
  const float4* anchors = (const float4*)d_in[2];
  const float4* gt      = (const float4*)d_in[3];
  int A = in_sizes[2] / 4;  // 100000

  char* ws = (char*)d_ws;
  Accum* acc = (Accum*)ws;
  size_t off_hc = (sizeof(Accum) + 255) & ~(size_t)255;
  unsigned int* ghc = (unsigned int*)(ws + off_hc);
  size_t off_hs = off_hc + (size_t)BN * NB * sizeof(unsigned int);
  float* ghs = (float*)(ws + off_hs);
  size_t off_part = off_hs + (size_t)BN * NB * sizeof(float);
  unsigned long long* partial = (unsigned long long*)(ws + off_part);
  // partial (GX*512 u64) is fully written by k_main each call; no memset.

  hipMemsetAsync(ws, 0, off_part, stream);  // Accum(+ticket+rowres) + hists

  dim3 grid(GX, BN);
  k_main<<<grid, BLK, 0, stream>>>(labels, poffs, anchors, gt, acc, partial,
                                   ghc, ghs, A);
  k_post<<<BN, BLK, 0, stream>>>(labels, poffs, anchors, gt, acc, partial,
                                 ghc, ghs, (float*)d_out, A, GX);
}

// Round 11
// 95.661 us; speedup vs baseline: 2.1399x; 1.3568x over previous
//
#include <hip/hip_runtime.h>
#include <math.h>

#define BN    16
#define NGTC  32
#define NB    2048      // 11-bit value buckets: float_bits >> 21
#define BSH   21
#define BLK   256
#define GX    64        // k_main blocks per batch row
#define CNTSH 40        // count field shift in packed u64 histogram
#define FPS   1048576.0f // 2^20 fixed-point scale for packed sum

struct Accum {
  unsigned int npos[BN];
  float pos_sum;
  float box_sum;
  unsigned int counter;     // k_post 16-block ticket
  unsigned int rw_np[BN];   // per-row corrected n_pos (k_post)
  float rw_hard[BN];        // per-row hard-negative sum (k_post)
};

__device__ inline float wred_sum_f(float v) {
#pragma unroll
  for (int o = 32; o > 0; o >>= 1) v += __shfl_down(v, o, 64);
  return v;
}
__device__ inline unsigned wred_sum_u(unsigned v) {
#pragma unroll
  for (int o = 32; o > 0; o >>= 1) v += __shfl_down(v, o, 64);
  return v;
}
__device__ inline float sl1(float d) {
  float ad = fabsf(d);
  return ad < 1.f ? 0.5f * d * d : ad - 0.5f;
}
// Same code in k_main and k_post so correction swaps cancel bit-exactly.
__device__ inline float boxterm(float4 av, float4 g, float4 p) {
  float acx = (av.x + av.z) * 0.5f, acy = (av.y + av.w) * 0.5f;
  float aw = av.z - av.x, ah = av.w - av.y;
  float gcx = (g.x + g.z) * 0.5f, gcy = (g.y + g.w) * 0.5f;
  float gw = g.z - g.x, gh = g.w - g.y;
  float t0 = (gcx - acx) / (aw / 10.f);
  float t1 = (gcy - acy) / (ah / 10.f);
  float t2 = __logf(gw / aw) * 5.f;
  float t3 = __logf(gh / ah) * 5.f;
  return sl1(p.x - t0) + sl1(p.y - t1) + sl1(p.z - t2) + sl1(p.w - t3);
}
// Agent-scope loads (k_post cross-block final combine, same kernel).
__device__ inline unsigned aload_u(const unsigned* p) {
  return __hip_atomic_load(p, __ATOMIC_RELAXED, __HIP_MEMORY_SCOPE_AGENT);
}
__device__ inline float aload_f(const float* p) {
  return __hip_atomic_load(p, __ATOMIC_RELAXED, __HIP_MEMORY_SCOPE_AGENT);
}

// Fused main pass. Measured lessons:
//  (R4) no min-waves in launch_bounds (VGPR cap -> scratch spills).
//  (R5) no read-guard on ds atomics; cap unroll (full unroll -> 176 VGPR).
//  (R9) VALU-issue-bound: fold the 2 anchors' per-GT candidates with one
//       exact cross-mult compare, then ONE rcp+pack+ds_atomic per jj.
__global__ __launch_bounds__(BLK) void k_main(
    const float* __restrict__ labels, const float4* __restrict__ poffs,
    const float4* __restrict__ anchors, const float4* __restrict__ gt,
    Accum* __restrict__ acc, unsigned long long* __restrict__ partial,
    unsigned int* __restrict__ ghc, float* __restrict__ ghs, int A) {
  __shared__ unsigned long long hist[NB];   // (count<<40) | fixedpoint-sum
  __shared__ unsigned long long sbest[NGTC];
  __shared__ float4 sgt[NGTC];
  __shared__ float sredf[BLK / 64], sredb[BLK / 64];
  __shared__ unsigned sredu[BLK / 64];
  int b = blockIdx.y, t = threadIdx.x;
  for (int i = t; i < NB; i += BLK) hist[i] = 0ull;
  if (t < NGTC) { sgt[t] = gt[b * NGTC + t]; sbest[t] = 0ull; }
  __syncthreads();

  float psum = 0.f, bsum = 0.f;
  unsigned cnt = 0u;
  int rot = t & 31;
  for (int a0 = blockIdx.x * (2 * BLK) + t; a0 < A; a0 += GX * 2 * BLK) {
    int a1 = a0 + BLK;
    bool v1 = a1 < A;
    float4 av0 = anchors[a0];
    // invalid -> degenerate far box: inter==0 with every gt
    float4 av1 = v1 ? anchors[a1] : make_float4(2.f, 2.f, 2.f, 2.f);
    float area0 = (av0.z - av0.x) * (av0.w - av0.y);
    float area1 = (av1.z - av1.x) * (av1.w - av1.y);
    unsigned na0 = ~(unsigned)a0, na1 = ~(unsigned)a1;
    float bn0 = -1.f, bd0 = 1.f, bn1 = -1.f, bd1 = 1.f;
    int gid0 = 0, gid1 = 0;
#pragma unroll 8
    for (int jj = 0; jj < NGTC; ++jj) {
      int j = (jj + rot) & 31;    // stagger lanes across the 32 sbest slots
      float4 g = sgt[j];
      float ga = (g.z - g.x) * (g.w - g.y);
      float w0 = fmaxf(fminf(av0.z, g.z) - fmaxf(av0.x, g.x), 0.f);
      float h0 = fmaxf(fminf(av0.w, g.w) - fmaxf(av0.y, g.y), 0.f);
      float i0 = w0 * h0;
      float d0 = area0 + ga - i0;
      if (i0 * bd0 > bn0 * d0) { bn0 = i0; bd0 = d0; gid0 = j; }
      float w1 = fmaxf(fminf(av1.z, g.z) - fmaxf(av1.x, g.x), 0.f);
      float h1 = fmaxf(fminf(av1.w, g.w) - fmaxf(av1.y, g.y), 0.f);
      float i1 = w1 * h1;
      float d1 = area1 + ga - i1;
      if (i1 * bd1 > bn1 * d1) { bn1 = i1; bd1 = d1; gid1 = j; }
      // fold the two candidates exactly (i1/d1 > i0/d0 <=> i1*d0 > i0*d1;
      // strict > keeps a0 = smaller index on ties, matching first-argmax)
      bool take1 = i1 * d0 > i0 * d1;
      float iw = take1 ? i1 : i0;
      float dw = take1 ? d1 : d0;
      unsigned naw = take1 ? na1 : na0;
      if (iw > 0.f) {
        float iou = iw * __builtin_amdgcn_rcpf(dw);  // ordering key only
        atomicMax(&sbest[j],
                  (((unsigned long long)__float_as_uint(iou)) << 32) | naw);
      }
    }
#pragma unroll
    for (int q = 0; q < 2; ++q) {
      int a = q ? a1 : a0;
      if (q && !v1) break;
      float4 av = q ? av1 : av0;
      float bn = q ? bn1 : bn0, bd = q ? bd1 : bd0;
      int gid = q ? gid1 : gid0;
      bool pos = bn > 0.3f * bd;
      float x = labels[(size_t)b * A + a];
      float e = __expf(-fabsf(x));
      float sp = fmaxf(x, 0.f) + __logf(1.f + e);   // softplus = bce(y=0)
      if (pos) {
        cnt++; psum += sp - x;                       // bce(y=1)
        float4 p = poffs[(size_t)b * A + a];
        bsum += boxterm(av, sgt[gid], p);
      } else {
        unsigned bk = __float_as_uint(sp) >> BSH;
        atomicAdd(&hist[bk],
                  (1ull << CNTSH) + (unsigned long long)(unsigned)(sp * FPS + 0.5f));
      }
    }
  }
  __syncthreads();
  if (t < NGTC)
    partial[(size_t)blockIdx.x * (BN * NGTC) + b * NGTC + t] = sbest[t];

  psum = wred_sum_f(psum);
  bsum = wred_sum_f(bsum);
  cnt  = wred_sum_u(cnt);
  int wid = t >> 6, lane = t & 63;
  if (lane == 0) { sredf[wid] = psum; sredb[wid] = bsum; sredu[wid] = cnt; }
  __syncthreads();
  if (t == 0) {
    float ps = 0.f, bs = 0.f; unsigned c = 0;
#pragma unroll
    for (int w2 = 0; w2 < BLK / 64; ++w2) { ps += sredf[w2]; bs += sredb[w2]; c += sredu[w2]; }
    if (c) atomicAdd(&acc->npos[b], c);
    atomicAdd(&acc->pos_sum, ps);
    atomicAdd(&acc->box_sum, bs);
  }
  for (int i = t; i < NB; i += BLK) {
    unsigned long long pk = hist[i];
    if (pk) {
      atomicAdd(&ghc[(size_t)b * NB + i], (unsigned)(pk >> CNTSH));
      atomicAdd(&ghs[(size_t)b * NB + i],
                (float)(pk & ((1ull << CNTSH) - 1ull)) * (1.f / FPS));
    }
  }
}

// Parallel epilogue: one block per batch row. Wave-parallel suffix scan
// finds the boundary chunk; the boundary thread hands {hard} to LDS; then
// t==0 UNCONDITIONALLY does writeback+ticket (R10 lesson: never gate the
// ticket on a data-dependent predicate — when k >= total negatives there is
// NO boundary thread and the reference takes ALL negatives = t0's total).
__global__ __launch_bounds__(BLK) void k_post(
    const float* __restrict__ labels, const float4* __restrict__ poffs,
    const float4* __restrict__ anchors, const float4* __restrict__ gt,
    Accum* __restrict__ acc, const unsigned long long* __restrict__ partial,
    const unsigned int* __restrict__ ghc, const float* __restrict__ ghs,
    float* __restrict__ out, int A, int nbx) {
  __shared__ unsigned hc[NB];
  __shared__ float    hsum[NB];
  __shared__ unsigned sa[NGTC];
  __shared__ float sdpos, sdbox;
  __shared__ unsigned sdnp;
  __shared__ unsigned sk;                  // 3 * corrected n_pos
  __shared__ unsigned swtc[BLK / 64];      // wave chunk-count totals
  __shared__ float    swts[BLK / 64];
  __shared__ float    srow_hard;
  __shared__ int      sdone;
  int b = blockIdx.x, t = threadIdx.x;

  // stage row histogram into LDS (coalesced) + reduce partial keys
  for (int i = t; i < NB; i += BLK) {
    hc[i] = ghc[(size_t)b * NB + i];
    hsum[i] = ghs[(size_t)b * NB + i];
  }
  if (t < NGTC) {
    unsigned long long best = 0ull;
    for (int i = 0; i < nbx; ++i) {
      unsigned long long v = partial[(size_t)i * (BN * NGTC) + b * NGTC + t];
      best = v > best ? v : best;
    }
    if (best == 0ull) best = 0xFFFFFFFFull;  // no overlap -> anchor 0
    sa[t] = ~(unsigned)(best & 0xFFFFFFFFull);
  }
  if (t == 0) { sdpos = 0.f; sdbox = 0.f; sdnp = 0u; sdone = 0; }
  __syncthreads();

  // forced-match corrections (threads 0..31, one per gt)
  if (t < NGTC) {
    unsigned a = sa[t];
    bool winner = true;
    for (int j2 = t + 1; j2 < NGTC; ++j2)
      if (sa[j2] == a) { winner = false; break; }  // last j wins
    if (winner) {
      // Replicate k_main's per-anchor pass EXACTLY (same rot, same op order).
      float4 avx = anchors[a];
      float area_a = (avx.z - avx.x) * (avx.w - avx.y);
      int rot = (int)(a & 31u);   // a == t (mod 256) in k_main, ILP stride 256
      float bn = -1.f, bd = 1.f;
      int gid = 0;
      for (int jj = 0; jj < NGTC; ++jj) {
        int j2 = (jj + rot) & 31;
        float4 g = gt[b * NGTC + j2];
        float ga = (g.z - g.x) * (g.w - g.y);
        float w = fmaxf(fminf(avx.z, g.z) - fmaxf(avx.x, g.x), 0.f);
        float h = fmaxf(fminf(avx.w, g.w) - fmaxf(avx.y, g.y), 0.f);
        float inter = w * h;
        float dj = area_a + ga - inter;
        if (inter * bd > bn * dj) { bn = inter; bd = dj; gid = j2; }
      }
      bool tpos = bn > 0.3f * bd;
      float4 p4 = poffs[(size_t)b * A + a];
      float newbox = boxterm(avx, gt[b * NGTC + t], p4);
      if (tpos) {
        if (gid != t) {   // box target overridden: swap terms
          float oldbox = boxterm(avx, gt[b * NGTC + gid], p4);
          atomicAdd(&sdbox, newbox - oldbox);
        }
      } else {            // was counted negative: promote to positive
        float x = labels[(size_t)b * A + a];
        float e = __expf(-fabsf(x));
        float sp = fmaxf(x, 0.f) + __logf(1.f + e);
        atomicAdd(&sdnp, 1u);
        atomicAdd(&sdpos, sp - x);
        atomicAdd(&sdbox, newbox);
        unsigned bk = __float_as_uint(sp) >> BSH;
        atomicSub(&hc[bk], 1u);
        atomicAdd(&hsum[bk], -sp);
      }
    }
  }
  __syncthreads();
  if (t == 0) sk = 3u * (acc->npos[b] + sdnp);

  // per-thread chunk sums (8 buckets each) in registers
  unsigned cth = 0; float sth = 0.f;
  {
    int base = t * (NB / BLK);
#pragma unroll
    for (int i = 0; i < NB / BLK; ++i) { cth += hc[base + i]; sth += hsum[base + i]; }
  }
  // wave-internal suffix-inclusive scan (descending index)
  int lane = t & 63, wv = t >> 6;
  unsigned S = cth; float Sf = sth;
#pragma unroll
  for (int off = 1; off < 64; off <<= 1) {
    unsigned cn = __shfl_down(S, off, 64);
    float sn = __shfl_down(Sf, off, 64);
    if (lane + off < 64) { S += cn; Sf += sn; }
  }
  if (lane == 0) { swtc[wv] = S; swts[wv] = Sf; }  // wave totals
  __syncthreads();
#pragma unroll
  for (int w2 = 0; w2 < BLK / 64; ++w2)
    if (w2 > wv) { S += swtc[w2]; Sf += swts[w2]; }
  // S/Sf for thread t = suffix over threads t..255; t0 holds the TOTAL.

  // boundary thread (unique when 1 <= k <= total): compute hard, hand off
  unsigned k = sk;
  if (k > 0u && S >= k && S - cth < k) {
    unsigned cum = S - cth;          // count strictly above my chunk
    float hard = Sf - sth;           // sum strictly above my chunk
    int base = t * (NB / BLK);
    for (int u = NB / BLK - 1; u >= 0; --u) {
      int bk = base + u;
      unsigned c2 = hc[bk];
      if (cum + c2 >= k) {
        unsigned r = k - cum;
        if (c2 && r) {
          float m  = hsum[bk] / (float)c2;
          float lo = __uint_as_float((unsigned)bk << BSH);
          float hi = __uint_as_float((unsigned)(bk + 1) << BSH);
          // uniform-within-bucket model; exact at r==c2
          hard += (float)r * m +
                  (float)r * (float)(c2 - r) * (hi - lo) / (2.f * (float)c2);
        }
        break;
      }
      cum += c2; hard += hsum[bk];
    }
    srow_hard = hard;
    sdone = 1;
  }
  __syncthreads();

  // t0 ALWAYS writes back and tickets (fallback: k >= total -> take all)
  if (t == 0) {
    float hard = sdone ? srow_hard : Sf;   // t0's Sf == total negative sum
    acc->rw_np[b] = k / 3u;
    acc->rw_hard[b] = hard;
    atomicAdd(&acc->pos_sum, sdpos);
    atomicAdd(&acc->box_sum, sdbox);
    __threadfence();
    unsigned tk = atomicAdd(&acc->counter, 1u);
    if (tk == BN - 1u) {       // last row block: final combine
      __threadfence();
      unsigned npt = 0; float hardt = 0.f;
      for (int bb = 0; bb < BN; ++bb) {
        npt += aload_u(&acc->rw_np[bb]);
        hardt += aload_f(&acc->rw_hard[bb]);
      }
      float npf = (float)npt;
      float box = aload_f(&acc->box_sum) / (npf * 4.f);
      float cls = (hardt + aload_f(&acc->pos_sum)) / npf;
      out[0] = box + cls;
      out[1] = box;
      out[2] = cls;
    }
  }
}

extern "C" void kernel_launch(void* const* d_in, const int* in_sizes, int n_in,
                              void* d_out, int out_size, void* d_ws, size_t ws_size,
                              hipStream_t stream) {
  const float*  labels  = (const float*)d_in[0];
  const float4* poffs   = (const float4*)d_in[1];
  const float4* anchors = (const float4*)d_in[2];
  const float4* gt      = (const float4*)d_in[3];
  int A = in_sizes[2] / 4;  // 100000

  char* ws = (char*)d_ws;
  Accum* acc = (Accum*)ws;
  size_t off_hc = (sizeof(Accum) + 255) & ~(size_t)255;
  unsigned int* ghc = (unsigned int*)(ws + off_hc);
  size_t off_hs = off_hc + (size_t)BN * NB * sizeof(unsigned int);
  float* ghs = (float*)(ws + off_hs);
  size_t off_part = off_hs + (size_t)BN * NB * sizeof(float);
  unsigned long long* partial = (unsigned long long*)(ws + off_part);
  // partial (GX*512 u64) is fully written by k_main each call; no memset.

  hipMemsetAsync(ws, 0, off_part, stream);  // Accum(+ticket+rowres) + hists

  dim3 grid(GX, BN);
  k_main<<<grid, BLK, 0, stream>>>(labels, poffs, anchors, gt, acc, partial,
                                   ghc, ghs, A);
  k_post<<<BN, BLK, 0, stream>>>(labels, poffs, anchors, gt, acc, partial,
                                 ghc, ghs, (float*)d_out, A, GX);
}